// Round 2
// baseline (5143.151 us; speedup 1.0000x reference)
//
#include <hip/hip_runtime.h>
#include <cstdint>
#include <cstddef>

// Model constants
static constexpr int kD   = 768;
static constexpr int kHD  = 64;
static constexpr int kNH  = 12;
static constexpr int kT   = 512;
static constexpr int kB   = 4;
static constexpr int kRows = kB * kT;        // 2048
static constexpr int kV   = 50257;
static constexpr int kL   = 6;
static constexpr int kFF  = 3072;
static constexpr float kEps = 1e-5f;

typedef short bf16x8 __attribute__((ext_vector_type(8)));
typedef float f32x4  __attribute__((ext_vector_type(4)));
typedef unsigned short u16;
typedef unsigned short u16x4 __attribute__((ext_vector_type(4)));
typedef unsigned short u16x8 __attribute__((ext_vector_type(8)));
typedef _Float16 f16x8 __attribute__((ext_vector_type(8)));

// ---------------------------------------------------------------------------
// fp32 -> bf16 hi/lo split:  a ~= hi + lo,  |err| <= 2^-17 |a|
// ---------------------------------------------------------------------------
__device__ __forceinline__ void split1(float a, u16& h, u16& l)
{
    unsigned u = __float_as_uint(a);
    h = (u16)(u >> 16);
    float fh = __uint_as_float(u & 0xFFFF0000u);
    float r = a - fh;                       // exact in fp32
    unsigned v = __float_as_uint(r);
    l = (u16)((v + 0x7FFFu + ((v >> 16) & 1u)) >> 16);
}

__device__ __forceinline__ u16 f16bits(float v)
{
    _Float16 t = (_Float16)v;
    return __builtin_bit_cast(u16, t);
}

// ---------------------------------------------------------------------------
// Embedding
// ---------------------------------------------------------------------------
__global__ __launch_bounds__(256) void embed_kernel(
    const int* __restrict__ ids, const float* __restrict__ tok,
    const float* __restrict__ pos, float* __restrict__ x)
{
    int i = blockIdx.x * 256 + threadIdx.x;
    if (i >= kRows * kD) return;
    int row = i / kD, d = i - row * kD;
    x[i] = tok[(size_t)ids[row] * kD + d] + pos[(row % kT) * kD + d];
}

// ---------------------------------------------------------------------------
// LayerNorm fused with bf16 hi/lo split output (GEMM A operand)
// ---------------------------------------------------------------------------
__global__ __launch_bounds__(256) void ln_split_kernel(
    const float* __restrict__ x, const float* __restrict__ g,
    const float* __restrict__ b, u16* __restrict__ ohi, u16* __restrict__ olo)
{
    const int row = blockIdx.x;
    const float* xr = x + (size_t)row * kD;
    float s = 0.f, ss = 0.f;
    for (int d = threadIdx.x; d < kD; d += 256) {
        float v = xr[d];
        s += v; ss += v * v;
    }
    #pragma unroll
    for (int off = 32; off; off >>= 1) {
        s  += __shfl_xor(s, off);
        ss += __shfl_xor(ss, off);
    }
    __shared__ float sh_s[4], sh_ss[4];
    const int wid = threadIdx.x >> 6, lane = threadIdx.x & 63;
    if (lane == 0) { sh_s[wid] = s; sh_ss[wid] = ss; }
    __syncthreads();
    s  = sh_s[0] + sh_s[1] + sh_s[2] + sh_s[3];
    ss = sh_ss[0] + sh_ss[1] + sh_ss[2] + sh_ss[3];
    const float mean = s * (1.0f / kD);
    const float var  = ss * (1.0f / kD) - mean * mean;
    const float rstd = rsqrtf(var + kEps);
    const size_t base = (size_t)row * kD;
    for (int d = threadIdx.x; d < kD; d += 256) {
        float val = (xr[d] - mean) * rstd * g[d] + b[d];
        u16 h1, l1; split1(val, h1, l1);
        ohi[base + d] = h1; olo[base + d] = l1;
    }
}

// ---------------------------------------------------------------------------
// fp32 -> fp16 convert (logits GEMM A operand). grid = n/1024.
// ---------------------------------------------------------------------------
__global__ __launch_bounds__(256) void cvt16_kernel(
    const float* __restrict__ in, u16* __restrict__ out)
{
    const int i = blockIdx.x * 256 + threadIdx.x;
    float4 v = ((const float4*)in)[i];
    u16x4 o;
    o[0] = f16bits(v.x); o[1] = f16bits(v.y);
    o[2] = f16bits(v.z); o[3] = f16bits(v.w);
    ((u16x4*)out)[i] = o;
}

// ---------------------------------------------------------------------------
// Repack per-layer QKV weights into W [768 x 2304] and bias[2304]
// ---------------------------------------------------------------------------
__global__ __launch_bounds__(256) void repack_qkv_kernel(
    const float* __restrict__ wk, const float* __restrict__ wq,
    const float* __restrict__ wv, const float* __restrict__ bk,
    const float* __restrict__ bq, const float* __restrict__ bv,
    float* __restrict__ Wp, float* __restrict__ Bp)
{
    int i = blockIdx.x * 256 + threadIdx.x;
    if (i < 3 * kD) {
        int which = i / kD, c = i - which * kD;
        const float* bsrc = (which == 0) ? bk : (which == 1) ? bq : bv;
        Bp[i] = bsrc[c];
    }
    if (i >= kD * 3 * kD) return;
    int col = i % (3 * kD), d = i / (3 * kD);
    int which = col / kD, hc = col - which * kD;   // hc = h*64+e
    const float* src = (which == 0) ? wk : (which == 1) ? wq : wv;
    Wp[i] = src[(size_t)(hc >> 6) * (kD * kHD) + (size_t)d * kHD + (hc & 63)];
}

// ---------------------------------------------------------------------------
// bf16x3 MFMA GEMM (layer GEMMs): out = A@W (+bias)(+resid)(relu?)
// LDS layout [fg][row][8] (k-group-major) -> conflict-free ds_read_b128.
// Output either fp32 (out) or fused bf16 hi/lo split (ohi/olo).
// ---------------------------------------------------------------------------
template<int BM>
__global__ __launch_bounds__(256) void gemm3_kernel(
    const u16* __restrict__ Ahi, const u16* __restrict__ Alo,
    const float* __restrict__ W, const float* __restrict__ bias,
    const float* __restrict__ resid, float* __restrict__ out,
    u16* __restrict__ ohi, u16* __restrict__ olo,
    int N, int K, int relu)
{
    __shared__ u16 Ah[4][BM][8], Al[4][BM][8];
    __shared__ u16 Bh[4][128][8], Bl[4][128][8];
    const int tid = threadIdx.x;
    const int m0 = blockIdx.y * BM;
    const int n0 = blockIdx.x * 128;
    const int wid = tid >> 6, lane = tid & 63;
    const int wr = wid >> 1, wc = wid & 1;
    const int fr = lane & 15, fg = lane >> 4;
    constexpr int MF = BM / 32;

    f32x4 acc[MF][4];
    #pragma unroll
    for (int i = 0; i < MF; ++i)
        #pragma unroll
        for (int j = 0; j < 4; ++j) acc[i][j] = (f32x4){0.f, 0.f, 0.f, 0.f};

    const int bc = tid & 127;
    const int bg2 = tid >> 7;              // 0..1
    const bool cval = (n0 + bc) < N;

    for (int k0 = 0; k0 < K; k0 += 32) {
        // ---- stage A (pre-split bf16): [fg][row][8]
        for (int i = tid; i < BM * 4; i += 256) {
            const int r = i >> 2, q = i & 3;
            const size_t off = (size_t)(m0 + r) * K + k0 + (q << 3);
            *(u16x8*)&Ah[q][r][0] = *(const u16x8*)(Ahi + off);
            *(u16x8*)&Al[q][r][0] = *(const u16x8*)(Alo + off);
        }
        // ---- stage B: coalesced fp32 loads, split, k-contig u16x8 stores
        #pragma unroll
        for (int f8 = 0; f8 < 2; ++f8) {
            const int q = (bg2 << 1) + f8;
            u16x8 hh, ll;
            #pragma unroll
            for (int j = 0; j < 8; ++j) {
                float v = cval ? W[(size_t)(k0 + (q << 3) + j) * N + (n0 + bc)] : 0.f;
                u16 h1, l1; split1(v, h1, l1);
                hh[j] = h1; ll[j] = l1;
            }
            *(u16x8*)&Bh[q][bc][0] = hh;
            *(u16x8*)&Bl[q][bc][0] = ll;
        }
        __syncthreads();

        bf16x8 ah[MF], al[MF], bh[4], bl[4];
        #pragma unroll
        for (int f = 0; f < MF; ++f) {
            const int row = wr * (BM / 2) + (f << 4) + fr;
            ah[f] = *(const bf16x8*)&Ah[fg][row][0];
            al[f] = *(const bf16x8*)&Al[fg][row][0];
        }
        #pragma unroll
        for (int f = 0; f < 4; ++f) {
            const int col = (wc << 6) + (f << 4) + fr;
            bh[f] = *(const bf16x8*)&Bh[fg][col][0];
            bl[f] = *(const bf16x8*)&Bl[fg][col][0];
        }
        #pragma unroll
        for (int i = 0; i < MF; ++i)
            #pragma unroll
            for (int j = 0; j < 4; ++j) {
                acc[i][j] = __builtin_amdgcn_mfma_f32_16x16x32_bf16(ah[i], bh[j], acc[i][j], 0, 0, 0);
                acc[i][j] = __builtin_amdgcn_mfma_f32_16x16x32_bf16(ah[i], bl[j], acc[i][j], 0, 0, 0);
                acc[i][j] = __builtin_amdgcn_mfma_f32_16x16x32_bf16(al[i], bh[j], acc[i][j], 0, 0, 0);
            }
        __syncthreads();
    }

    #pragma unroll
    for (int i = 0; i < MF; ++i) {
        const int mb = m0 + wr * (BM / 2) + (i << 4) + (fg << 2);
        #pragma unroll
        for (int j = 0; j < 4; ++j) {
            const int n = n0 + (wc << 6) + (j << 4) + fr;
            if (n < N) {
                const float bvv = bias ? bias[n] : 0.f;
                #pragma unroll
                for (int r = 0; r < 4; ++r) {
                    const size_t oo = (size_t)(mb + r) * N + n;
                    float vv = acc[i][j][r] + bvv;
                    if (resid) vv += resid[oo];
                    if (relu)  vv = fmaxf(vv, 0.f);
                    if (ohi) { u16 h1, l1; split1(vv, h1, l1); ohi[oo] = h1; olo[oo] = l1; }
                    else     out[oo] = vv;
                }
            }
        }
    }
}

// ---------------------------------------------------------------------------
// fp16 single-pass MFMA GEMM for logits: out[M,N] = A@W + bias (fp32 out)
// 256x128 tile, 512 threads (8 waves, 4x2), BK=32. A pre-converted fp16.
// grid: (M/256 = 8, ceil(N/128)) -- m-major so same-W-panel blocks adjacent.
// ---------------------------------------------------------------------------
__global__ __launch_bounds__(512) void gemmh_kernel(
    const u16* __restrict__ Axh, const float* __restrict__ W,
    const float* __restrict__ bias, float* __restrict__ out, int N, int K)
{
    __shared__ _Float16 Ah[4][256][8];
    __shared__ _Float16 Bh[4][128][8];
    const int tid = threadIdx.x;
    const int m0 = blockIdx.x * 256;
    const int n0 = blockIdx.y * 128;
    const int wid = tid >> 6, lane = tid & 63;
    const int wr = wid >> 1, wc = wid & 1;       // 4 x 2 wave grid
    const int fr = lane & 15, fg = lane >> 4;

    f32x4 acc[4][4];
    #pragma unroll
    for (int i = 0; i < 4; ++i)
        #pragma unroll
        for (int j = 0; j < 4; ++j) acc[i][j] = (f32x4){0.f, 0.f, 0.f, 0.f};

    const int bc = tid & 127, bg = tid >> 7;     // col, k-group 0..3
    const bool cval = (n0 + bc) < N;

    for (int k0 = 0; k0 < K; k0 += 32) {
        // stage A: 1024 u16x8 groups over 512 threads
        for (int i = tid; i < 1024; i += 512) {
            const int r = i >> 2, q = i & 3;
            *(u16x8*)&Ah[q][r][0] =
                *(const u16x8*)(Axh + (size_t)(m0 + r) * K + k0 + (q << 3));
        }
        // stage B: 8 coalesced fp32 loads, cvt fp16, one 16B store
        {
            f16x8 hv;
            #pragma unroll
            for (int j = 0; j < 8; ++j) {
                float v = cval ? W[(size_t)(k0 + (bg << 3) + j) * N + (n0 + bc)] : 0.f;
                hv[j] = (_Float16)v;
            }
            *(f16x8*)&Bh[bg][bc][0] = hv;
        }
        __syncthreads();

        f16x8 a[4], bb[4];
        #pragma unroll
        for (int f = 0; f < 4; ++f)
            a[f] = *(const f16x8*)&Ah[fg][(wr << 6) + (f << 4) + fr][0];
        #pragma unroll
        for (int j = 0; j < 4; ++j)
            bb[j] = *(const f16x8*)&Bh[fg][(wc << 6) + (j << 4) + fr][0];
        #pragma unroll
        for (int f = 0; f < 4; ++f)
            #pragma unroll
            for (int j = 0; j < 4; ++j)
                acc[f][j] = __builtin_amdgcn_mfma_f32_16x16x32_f16(a[f], bb[j], acc[f][j], 0, 0, 0);
        __syncthreads();
    }

    #pragma unroll
    for (int f = 0; f < 4; ++f) {
        const int mb = m0 + (wr << 6) + (f << 4) + (fg << 2);
        #pragma unroll
        for (int j = 0; j < 4; ++j) {
            const int n = n0 + (wc << 6) + (j << 4) + fr;
            if (n < N) {
                const float bvv = bias[n];
                #pragma unroll
                for (int r = 0; r < 4; ++r)
                    out[(size_t)(mb + r) * N + n] = acc[f][j][r] + bvv;
            }
        }
    }
}

// ---------------------------------------------------------------------------
// Tiled flash-style attention (unchanged core), fused bf16 split output.
// ---------------------------------------------------------------------------
__global__ __launch_bounds__(256) void attn2_kernel(
    const float* __restrict__ qkv, u16* __restrict__ ohi, u16* __restrict__ olo)
{
    __shared__ float KbT[64][64];
    __shared__ float QbT[64][64];
    __shared__ float Vb[64][64];
    __shared__ float Pt[64][64];
    const int tb = gridDim.x - 1 - blockIdx.x;   // heavy blocks first
    const int hh = blockIdx.y, b = blockIdx.z;
    const int t0 = tb << 6;
    const int tid = threadIdx.x;
    const int ty = tid >> 4, tx = tid & 15;
    const int sr = tid >> 2;
    const int se0 = (tid & 3) << 4;
    const size_t rb = (size_t)b * kT;

    {   // stage K transposed: KbT[e][t]
        const float* ks = qkv + (rb + t0 + sr) * (3 * kD) + hh * kHD + se0;
        #pragma unroll
        for (int j = 0; j < 16; j += 4) {
            float4 v = *(const float4*)(ks + j);
            KbT[se0 + j + 0][sr] = v.x;
            KbT[se0 + j + 1][sr] = v.y;
            KbT[se0 + j + 2][sr] = v.z;
            KbT[se0 + j + 3][sr] = v.w;
        }
    }

    float m[4], l[4], O[4][4];
    #pragma unroll
    for (int i = 0; i < 4; ++i) {
        m[i] = -INFINITY; l[i] = 0.f;
        #pragma unroll
        for (int j = 0; j < 4; ++j) O[i][j] = 0.f;
    }

    for (int s0 = 0; s0 <= t0; s0 += 64) {
        __syncthreads();
        {   // stage Q transposed + V (swizzled quads)
            const float* qs = qkv + (rb + s0 + sr) * (3 * kD) + kD + hh * kHD + se0;
            #pragma unroll
            for (int j = 0; j < 16; j += 4) {
                float4 v = *(const float4*)(qs + j);
                QbT[se0 + j + 0][sr] = v.x;
                QbT[se0 + j + 1][sr] = v.y;
                QbT[se0 + j + 2][sr] = v.z;
                QbT[se0 + j + 3][sr] = v.w;
            }
            const float* vs = qkv + (rb + s0 + sr) * (3 * kD) + 2 * kD + hh * kHD + se0;
            #pragma unroll
            for (int jq = 0; jq < 4; ++jq) {
                const int c4 = (se0 >> 2) + jq;
                *(float4*)&Vb[sr][(c4 ^ (sr & 15)) << 2] = *(const float4*)(vs + (jq << 2));
            }
        }
        __syncthreads();

        float S[4][4];
        #pragma unroll
        for (int i = 0; i < 4; ++i)
            #pragma unroll
            for (int j = 0; j < 4; ++j) S[i][j] = 0.f;

        #pragma unroll 8
        for (int e = 0; e < 64; ++e) {
            float4 ka = *(const float4*)&KbT[e][ty << 2];
            float4 qa = *(const float4*)&QbT[e][tx << 2];
            float a[4] = {ka.x, ka.y, ka.z, ka.w};
            float q[4] = {qa.x, qa.y, qa.z, qa.w};
            #pragma unroll
            for (int i = 0; i < 4; ++i)
                #pragma unroll
                for (int j = 0; j < 4; ++j)
                    S[i][j] = fmaf(a[i], q[j], S[i][j]);
        }

        if (s0 == t0) {
            #pragma unroll
            for (int i = 0; i < 4; ++i)
                #pragma unroll
                for (int j = 0; j < 4; ++j)
                    if (((tx << 2) + j) > ((ty << 2) + i)) S[i][j] = -INFINITY;
        }

        float p[4][4];
        #pragma unroll
        for (int i = 0; i < 4; ++i) {
            float mx = fmaxf(fmaxf(S[i][0], S[i][1]), fmaxf(S[i][2], S[i][3]));
            #pragma unroll
            for (int off = 1; off < 16; off <<= 1)
                mx = fmaxf(mx, __shfl_xor(mx, off));
            const float nm = fmaxf(m[i], mx);
            const float sc = __expf(m[i] - nm);
            float rs = 0.f;
            #pragma unroll
            for (int j = 0; j < 4; ++j) { p[i][j] = __expf(S[i][j] - nm); rs += p[i][j]; }
            #pragma unroll
            for (int off = 1; off < 16; off <<= 1) rs += __shfl_xor(rs, off);
            l[i] = l[i] * sc + rs;
            m[i] = nm;
            #pragma unroll
            for (int j = 0; j < 4; ++j) O[i][j] *= sc;
        }
        #pragma unroll
        for (int j = 0; j < 4; ++j) {
            const int scol = (tx << 2) + j;
            float4 pv = make_float4(p[0][j], p[1][j], p[2][j], p[3][j]);
            *(float4*)&Pt[scol][(ty ^ (scol & 15)) << 2] = pv;
        }
        __syncthreads();

        #pragma unroll 8
        for (int s = 0; s < 64; ++s) {
            float4 pa = *(const float4*)&Pt[s][(ty ^ (s & 15)) << 2];
            float4 va = *(const float4*)&Vb[s][(tx ^ (s & 15)) << 2];
            float a[4] = {pa.x, pa.y, pa.z, pa.w};
            float v[4] = {va.x, va.y, va.z, va.w};
            #pragma unroll
            for (int i = 0; i < 4; ++i)
                #pragma unroll
                for (int j = 0; j < 4; ++j)
                    O[i][j] = fmaf(a[i], v[j], O[i][j]);
        }
    }

    #pragma unroll
    for (int i = 0; i < 4; ++i) {
        const float inv = 1.0f / l[i];
        const size_t oo = (rb + t0 + (ty << 2) + i) * kD + hh * kHD + (tx << 2);
        u16x4 oh, ol;
        #pragma unroll
        for (int j = 0; j < 4; ++j) {
            u16 h1, l1; split1(O[i][j] * inv, h1, l1);
            oh[j] = h1; ol[j] = l1;
        }
        *(u16x4*)&ohi[oo] = oh;
        *(u16x4*)&olo[oo] = ol;
    }
}

// ---------------------------------------------------------------------------
// Loss: single-pass online logsumexp per row
// ---------------------------------------------------------------------------
__global__ __launch_bounds__(256) void loss_kernel(
    const float* __restrict__ logits, const int* __restrict__ target,
    float* __restrict__ loss)
{
    const int row = blockIdx.x;
    const float* lr = logits + (size_t)row * kV;
    const int wid = threadIdx.x >> 6, lane = threadIdx.x & 63;
    __shared__ float redm[4], reds[4];

    float m = -INFINITY, s = 0.f;
    for (int i = threadIdx.x; i < kV; i += 256) {
        float v = lr[i];
        if (v <= m) {
            s += __expf(v - m);
        } else {
            s = s * __expf(m - v) + 1.f;
            m = v;
        }
    }
    #pragma unroll
    for (int off = 32; off; off >>= 1) {
        float mo = __shfl_xor(m, off), so = __shfl_xor(s, off);
        float nm = fmaxf(m, mo);
        s = s * __expf(m - nm) + so * __expf(mo - nm);
        m = nm;
    }
    if (lane == 0) { redm[wid] = m; reds[wid] = s; }
    __syncthreads();

    if (threadIdx.x == 0) {
        m = redm[0]; s = reds[0];
        #pragma unroll
        for (int w = 1; w < 4; ++w) {
            float nm = fmaxf(m, redm[w]);
            s = s * __expf(m - nm) + reds[w] * __expf(redm[w] - nm);
            m = nm;
        }
        float logZ = m + logf(s);
        float nll = logZ - lr[target[row]];
        atomicAdd(loss, nll * (1.0f / kRows));
    }
}

// ---------------------------------------------------------------------------
static inline void launch_gemm3_64(const u16* Ahi, const u16* Alo, const float* W,
                                   const float* bias, const float* resid,
                                   float* out, u16* ohi, u16* olo,
                                   int N, int K, int relu, hipStream_t stream)
{
    gemm3_kernel<64><<<dim3((N + 127) / 128, kRows / 64), 256, 0, stream>>>(
        Ahi, Alo, W, bias, resid, out, ohi, olo, N, K, relu);
}
static inline void launch_gemm3_128(const u16* Ahi, const u16* Alo, const float* W,
                                    const float* bias, const float* resid,
                                    float* out, u16* ohi, u16* olo,
                                    int N, int K, int relu, hipStream_t stream)
{
    gemm3_kernel<128><<<dim3((N + 127) / 128, kRows / 128), 256, 0, stream>>>(
        Ahi, Alo, W, bias, resid, out, ohi, olo, N, K, relu);
}

extern "C" void kernel_launch(void* const* d_in, const int* in_sizes, int n_in,
                              void* d_out, int out_size, void* d_ws, size_t ws_size,
                              hipStream_t stream)
{
    const int*   ids = (const int*)d_in[0];
    const int*   tgt = (const int*)d_in[1];
    const float* tok = (const float*)d_in[2];
    const float* pos = (const float*)d_in[3];
    const float* ipw = (const float*)d_in[4];
    const float* ipb = (const float*)d_in[5];
    const float* wk  = (const float*)d_in[6];
    const float* bk  = (const float*)d_in[7];
    const float* wq  = (const float*)d_in[8];
    const float* bq  = (const float*)d_in[9];
    const float* wv  = (const float*)d_in[10];
    const float* bv  = (const float*)d_in[11];
    const float* opw = (const float*)d_in[12];
    const float* opb = (const float*)d_in[13];
    const float* fw1 = (const float*)d_in[14];
    const float* fb1 = (const float*)d_in[15];
    const float* fw2 = (const float*)d_in[16];
    const float* fb2 = (const float*)d_in[17];
    const float* lag = (const float*)d_in[18];
    const float* lab = (const float*)d_in[19];
    const float* lfg = (const float*)d_in[20];
    const float* lfb = (const float*)d_in[21];
    const float* outw = (const float*)d_in[22];
    const float* outb = (const float*)d_in[23];

    float* ws = (float*)d_ws;
    const size_t S = (size_t)kRows * kD;          // 1,572,864 floats
    float* x      = ws;                  // [S] fp32 residual stream
    float* hbuf   = x    + S;            // [S]  holds h split (2S u16) / xh fp16
    float* h2buf  = hbuf + S;            // [S]  h2 split
    float* atbbuf = h2buf + S;           // [S]  attn-out split
    float* qkv    = atbbuf + S;          // [3S] fp32
    float* ffhbuf = qkv  + 3 * S;        // [4S] ffh split (8S u16)
    float* wqkv   = ffhbuf + 4 * S;      // [768*2304]
    float* bqkv   = wqkv + (size_t)kD * 3 * kD;

    u16* h_hi  = (u16*)hbuf;   u16* h_lo  = h_hi  + S;
    u16* h2_hi = (u16*)h2buf;  u16* h2_lo = h2_hi + S;
    u16* at_hi = (u16*)atbbuf; u16* at_lo = at_hi + S;
    u16* ff_hi = (u16*)ffhbuf; u16* ff_lo = ff_hi + 4 * S;
    u16* xh    = (u16*)hbuf;   // fp16 x for logits (hbuf dead by then)

    float* logits = (float*)d_out;
    float* loss = logits + (size_t)kRows * kV;

    embed_kernel<<<(kRows * kD + 255) / 256, 256, 0, stream>>>(ids, tok, pos, x);

    const size_t wsz = (size_t)kD * kD;
    const size_t fsz = (size_t)kD * kFF;
    for (int l = 0; l < kL; ++l) {
        ln_split_kernel<<<kRows, 256, 0, stream>>>(x, lag + l * kD, lab + l * kD,
                                                   h_hi, h_lo);
        launch_gemm3_64(h_hi, h_lo, ipw + l * wsz, ipb + l * kD, nullptr,
                        nullptr, h2_hi, h2_lo, kD, kD, 0, stream);
        repack_qkv_kernel<<<(kD * 3 * kD + 255) / 256, 256, 0, stream>>>(
            wk + l * wsz, wq + l * wsz, wv + l * wsz,
            bk + l * kD, bq + l * kD, bv + l * kD, wqkv, bqkv);
        launch_gemm3_128(h2_hi, h2_lo, wqkv, bqkv, nullptr,
                         qkv, nullptr, nullptr, 3 * kD, kD, 0, stream);
        attn2_kernel<<<dim3(kT / 64, kNH, kB), 256, 0, stream>>>(qkv, at_hi, at_lo);
        launch_gemm3_64(at_hi, at_lo, opw + l * wsz, opb + l * kD, x,
                        x, nullptr, nullptr, kD, kD, 0, stream);
        ln_split_kernel<<<kRows, 256, 0, stream>>>(x, lfg + l * kD, lfb + l * kD,
                                                   h_hi, h_lo);
        launch_gemm3_128(h_hi, h_lo, fw1 + l * fsz, fb1 + l * kFF, nullptr,
                         nullptr, ff_hi, ff_lo, kFF, kD, 1, stream);
        launch_gemm3_64(ff_hi, ff_lo, fw2 + l * fsz, fb2 + l * kD, x,
                        x, nullptr, nullptr, kD, kFF, 0, stream);
    }
    cvt16_kernel<<<(int)(S / 1024), 256, 0, stream>>>(x, xh);
    // grid m-major: 8 m-blocks sharing a W n-panel are dispatch-adjacent
    gemmh_kernel<<<dim3(kRows / 256, (kV + 127) / 128), 512, 0, stream>>>(
        xh, outw, outb, logits, kV, kD);
    hipMemsetAsync(loss, 0, sizeof(float), stream);
    loss_kernel<<<kRows, 256, 0, stream>>>(logits, tgt, loss);
}